// Round 1
// baseline (438.843 us; speedup 1.0000x reference)
//
#include <hip/hip_runtime.h>

// SpikingLayer: B=16, T=128, feat = 32*32*32 = 32768 floats.
// Input/output both laid out as [(b*T + t) * FEAT + f].
// Each thread owns 4 consecutive neurons (one float4 lane) and runs the
// 128-step membrane scan sequentially; all timestep loads/stores are
// coalesced (wave of 64 lanes -> 1 KiB contiguous per instruction).

constexpr int T_STEPS = 128;
constexpr int FEAT    = 32 * 32 * 32;   // 32768
constexpr int FEATQ   = FEAT / 4;       // 8192 float4 per (b,t) plane

__global__ __launch_bounds__(256) void spiking_scan_kernel(
    const float4* __restrict__ in, float4* __restrict__ out)
{
    const int idx = blockIdx.x * 256 + threadIdx.x;     // 0 .. 131071
    const int b   = idx >> 13;                          // idx / FEATQ
    const int f   = idx & (FEATQ - 1);                  // idx % FEATQ
    const size_t base = (size_t)b * T_STEPS * FEATQ + (size_t)f;
    const float4* __restrict__ src = in  + base;
    float4*       __restrict__ dst = out + base;

    // membrane state + previous activation per neuron, init 0
    float s0 = 0.f, s1 = 0.f, s2 = 0.f, s3 = 0.f;
    float a0 = 0.f, a1 = 0.f, a2 = 0.f, a3 = 0.f;

    #pragma unroll 4
    for (int t = 0; t < T_STEPS; ++t) {
        const float4 syn = src[(size_t)t * FEATQ];

        // Replicate reference FP op order exactly:
        //   state = (syn + state) - act            (membrane_subtract = 1)
        //   state = max(state - (-1), 0) + (-1)    (lower clamp at -1)
        //   act   = state > 0 ? floor(state) : 0   (threshold = 1)
        s0 = (syn.x + s0) - a0;
        s1 = (syn.y + s1) - a1;
        s2 = (syn.z + s2) - a2;
        s3 = (syn.w + s3) - a3;

        s0 = fmaxf(s0 + 1.0f, 0.0f) - 1.0f;
        s1 = fmaxf(s1 + 1.0f, 0.0f) - 1.0f;
        s2 = fmaxf(s2 + 1.0f, 0.0f) - 1.0f;
        s3 = fmaxf(s3 + 1.0f, 0.0f) - 1.0f;

        a0 = (s0 > 0.0f) ? floorf(s0) : 0.0f;
        a1 = (s1 > 0.0f) ? floorf(s1) : 0.0f;
        a2 = (s2 > 0.0f) ? floorf(s2) : 0.0f;
        a3 = (s3 > 0.0f) ? floorf(s3) : 0.0f;

        float4 o;
        o.x = a0; o.y = a1; o.z = a2; o.w = a3;
        dst[(size_t)t * FEATQ] = o;
    }
}

extern "C" void kernel_launch(void* const* d_in, const int* in_sizes, int n_in,
                              void* d_out, int out_size, void* d_ws, size_t ws_size,
                              hipStream_t stream)
{
    (void)in_sizes; (void)n_in; (void)d_ws; (void)ws_size; (void)out_size;
    const float4* in  = (const float4*)d_in[0];
    float4*       out = (float4*)d_out;

    // 16 batches * 8192 quads = 131072 threads = 512 blocks of 256
    const int total_quads = 16 * FEATQ;
    const int block = 256;
    const int grid  = total_quads / block;   // 512
    spiking_scan_kernel<<<grid, block, 0, stream>>>(in, out);
}

// Round 2
// 422.120 us; speedup vs baseline: 1.0396x; 1.0396x over previous
//
#include <hip/hip_runtime.h>

// SpikingLayer scan: B=16, T=128, FEAT = 32*32*32 = 32768.
// Layout in/out: [(b*T + t) * FEAT + f].
// One thread per neuron (b,f): 524,288 threads = 256 CU * 2048 = full
// residency (8 waves/SIMD). Serial scan over T with register-staged,
// ping-pong prefetched input chunks (8 deep x 2 buffers) so ~16 loads
// per thread stay in flight across the state-dependency chain.

constexpr int T_STEPS = 128;
constexpr int FEAT    = 32 * 32 * 32;   // 32768
constexpr int CHUNK   = 8;
constexpr int NCHUNK  = T_STEPS / CHUNK; // 16

__global__ __launch_bounds__(256) void spiking_scan_kernel(
    const float* __restrict__ in, float* __restrict__ out)
{
    const int idx = blockIdx.x * 256 + threadIdx.x;   // 0 .. 524287
    const int b   = idx >> 15;                        // idx / FEAT
    const int f   = idx & (FEAT - 1);                 // idx % FEAT
    const size_t base = (size_t)b * T_STEPS * FEAT + (size_t)f;
    const float* __restrict__ src = in  + base;
    float*       __restrict__ dst = out + base;

    float s = 0.f, a = 0.f;
    float bufA[CHUNK], bufB[CHUNK];

    // prologue: chunk 0 -> bufA
    #pragma unroll
    for (int u = 0; u < CHUNK; ++u)
        bufA[u] = __builtin_nontemporal_load(&src[(size_t)u * FEAT]);

    for (int c = 0; c < NCHUNK; c += 2) {
        // prefetch chunk c+1 -> bufB (always valid: NCHUNK is even)
        #pragma unroll
        for (int u = 0; u < CHUNK; ++u)
            bufB[u] = __builtin_nontemporal_load(
                &src[(size_t)((c + 1) * CHUNK + u) * FEAT]);

        // process chunk c from bufA. Reference FP op order exactly:
        //   state = (syn + state) - act
        //   state = max(state + 1, 0) - 1
        //   act   = state > 0 ? floor(state) : 0
        #pragma unroll
        for (int u = 0; u < CHUNK; ++u) {
            s = (bufA[u] + s) - a;
            s = fmaxf(s + 1.0f, 0.0f) - 1.0f;
            a = (s > 0.0f) ? floorf(s) : 0.0f;
            __builtin_nontemporal_store(a, &dst[(size_t)(c * CHUNK + u) * FEAT]);
        }

        // prefetch chunk c+2 -> bufA
        if (c + 2 < NCHUNK) {
            #pragma unroll
            for (int u = 0; u < CHUNK; ++u)
                bufA[u] = __builtin_nontemporal_load(
                    &src[(size_t)((c + 2) * CHUNK + u) * FEAT]);
        }

        // process chunk c+1 from bufB
        #pragma unroll
        for (int u = 0; u < CHUNK; ++u) {
            s = (bufB[u] + s) - a;
            s = fmaxf(s + 1.0f, 0.0f) - 1.0f;
            a = (s > 0.0f) ? floorf(s) : 0.0f;
            __builtin_nontemporal_store(a, &dst[(size_t)((c + 1) * CHUNK + u) * FEAT]);
        }
    }
}

extern "C" void kernel_launch(void* const* d_in, const int* in_sizes, int n_in,
                              void* d_out, int out_size, void* d_ws, size_t ws_size,
                              hipStream_t stream)
{
    (void)in_sizes; (void)n_in; (void)d_ws; (void)ws_size; (void)out_size;
    const float* in  = (const float*)d_in[0];
    float*       out = (float*)d_out;

    // 16 * 32768 = 524288 threads = 2048 blocks of 256 (full residency)
    const int total = 16 * FEAT;
    const int block = 256;
    const int grid  = total / block;   // 2048
    spiking_scan_kernel<<<grid, block, 0, stream>>>(in, out);
}